// Round 1
// baseline (84.136 us; speedup 1.0000x reference)
//
#include <hip/hip_runtime.h>
#include <hip/hip_bf16.h>
#include <math.h>

#define H 1024
#define MAXLEN 128
#define VOCAB 50257

__device__ inline float wave_reduce_sum(float v) {
    #pragma unroll
    for (int off = 32; off > 0; off >>= 1) v += __shfl_down(v, off);
    return v;  // lane 0 holds the sum
}

// K1: attn logits[i] = dot(concat(e, h0), W_attn[i]) + b_attn[i], i in [0,128)
__global__ void k_attn_logits(const int* x, const float* h, const float* emb,
                              const float* W_attn, const float* b_attn, float* logits) {
    const int row = blockIdx.x;
    const float* w = W_attn + row * (2 * H);
    const float* e = emb + (long long)x[0] * H;
    float acc = 0.f;
    for (int k = threadIdx.x; k < 2 * H; k += blockDim.x) {
        float c = (k < H) ? e[k] : h[k - H];
        acc += c * w[k];
    }
    __shared__ float red[4];
    int lane = threadIdx.x & 63, wid = threadIdx.x >> 6;
    acc = wave_reduce_sum(acc);
    if (lane == 0) red[wid] = acc;
    __syncthreads();
    if (threadIdx.x == 0)
        logits[row] = red[0] + red[1] + red[2] + red[3] + b_attn[row];
}

// K2: softmax over 128 logits -> attn_w (ws) and d_out attn_w slot
__global__ void k_softmax128(const float* logits, float* attn_w, float* out_attn) {
    __shared__ float red[MAXLEN];
    int t = threadIdx.x;  // 128 threads
    float v = logits[t];
    red[t] = v;
    __syncthreads();
    for (int s = 64; s > 0; s >>= 1) { if (t < s) red[t] = fmaxf(red[t], red[t + s]); __syncthreads(); }
    float m = red[0];
    __syncthreads();
    float ex = expf(v - m);
    red[t] = ex;
    __syncthreads();
    for (int s = 64; s > 0; s >>= 1) { if (t < s) red[t] += red[t + s]; __syncthreads(); }
    float w = ex / red[0];
    attn_w[t] = w;
    out_attn[t] = w;
}

// K3: attn_applied[j] = sum_k attn_w[k] * enc[k][j]
__global__ void k_attn_apply(const float* attn_w, const float* enc, float* out) {
    __shared__ float w[MAXLEN];
    if (threadIdx.x < MAXLEN) w[threadIdx.x] = attn_w[threadIdx.x];
    __syncthreads();
    int j = blockIdx.x * blockDim.x + threadIdx.x;
    float acc = 0.f;
    #pragma unroll 8
    for (int k = 0; k < MAXLEN; k++) acc += w[k] * enc[k * H + j];
    out[j] = acc;
}

// K4: g[row] = relu(dot(concat(e, attn_applied), W_comb[row]) + b_comb[row]); one wave per row
__global__ void k_combine(const int* x, const float* emb, const float* attn_applied,
                          const float* W_comb, const float* b_comb, float* g) {
    int wid = threadIdx.x >> 6, lane = threadIdx.x & 63;
    int row = blockIdx.x * 4 + wid;
    const float4* w4 = (const float4*)(W_comb + (long long)row * (2 * H));
    const float4* e4 = (const float4*)(emb + (long long)x[0] * H);
    const float4* a4 = (const float4*)attn_applied;
    float acc = 0.f;
    #pragma unroll
    for (int i = 0; i < 8; i++) {
        int idx = lane + i * 64;  // float4 index into 512-wide row
        float4 wv = w4[idx];
        float4 cv = (idx < 256) ? e4[idx] : a4[idx - 256];
        acc += wv.x * cv.x + wv.y * cv.y + wv.z * cv.z + wv.w * cv.w;
    }
    acc = wave_reduce_sum(acc);
    if (lane == 0) g[row] = fmaxf(acc + b_comb[row], 0.f);
}

// K5: gi[i] = dot(g, w_ih[i]) + b_ih[i];  gh[i] = dot(h0, w_hh[i]) + b_hh[i]; one wave per row
__global__ void k_gru_mm(const float* g, const float* h,
                         const float* w_ih, const float* w_hh,
                         const float* b_ih, const float* b_hh,
                         float* gi, float* gh) {
    int wid = threadIdx.x >> 6, lane = threadIdx.x & 63;
    int gRow = blockIdx.x * 4 + wid;  // 0..6143
    const float* vec;
    const float* mat;
    const float* bias;
    float* out;
    int row;
    if (gRow < 3 * H) { row = gRow; vec = g; mat = w_ih; bias = b_ih; out = gi; }
    else { row = gRow - 3 * H; vec = h; mat = w_hh; bias = b_hh; out = gh; }
    const float4* w4 = (const float4*)(mat + (long long)row * H);
    const float4* v4 = (const float4*)vec;
    float acc = 0.f;
    #pragma unroll
    for (int i = 0; i < 4; i++) {
        int idx = lane + i * 64;
        float4 wv = w4[idx];
        float4 vv = v4[idx];
        acc += wv.x * vv.x + wv.y * vv.y + wv.z * vv.z + wv.w * vv.w;
    }
    acc = wave_reduce_sum(acc);
    if (lane == 0) out[row] = acc + bias[row];
}

// K6: GRU gate combine -> h_new (written to d_out h slot)
__global__ void k_gates(const float* gi, const float* gh, const float* h, float* h_new) {
    int j = threadIdx.x;  // 1024 threads
    float r = 1.f / (1.f + expf(-(gi[j] + gh[j])));
    float z = 1.f / (1.f + expf(-(gi[j + H] + gh[j + H])));
    float n = tanhf(gi[j + 2 * H] + r * gh[j + 2 * H]);
    h_new[j] = (1.f - z) * n + z * h[j];
}

// K7: logits[v] = dot(h_new, W_out[v]) + b_out[v]; one wave per row
__global__ void k_out_matvec(const float* hn, const float* W_out, const float* b_out, float* out) {
    int wid = threadIdx.x >> 6, lane = threadIdx.x & 63;
    int row = blockIdx.x * 4 + wid;
    if (row >= VOCAB) return;
    const float4* w4 = (const float4*)(W_out + (long long)row * H);
    const float4* h4 = (const float4*)hn;
    float acc = 0.f;
    #pragma unroll
    for (int i = 0; i < 4; i++) {
        int idx = lane + i * 64;
        float4 wv = w4[idx];
        float4 hv = h4[idx];
        acc += wv.x * hv.x + wv.y * hv.y + wv.z * hv.z + wv.w * hv.w;
    }
    acc = wave_reduce_sum(acc);
    if (lane == 0) out[row] = acc + b_out[row];
}

// K8: c = max(logits) + log(sum exp(logits - max))
__global__ void k_lse(const float* out, float* c) {
    __shared__ float red[16];
    __shared__ float Msh;
    int lane = threadIdx.x & 63, wid = threadIdx.x >> 6;
    float m = -1e30f;
    for (int i = threadIdx.x; i < VOCAB; i += blockDim.x) m = fmaxf(m, out[i]);
    #pragma unroll
    for (int off = 32; off > 0; off >>= 1) m = fmaxf(m, __shfl_down(m, off));
    if (lane == 0) red[wid] = m;
    __syncthreads();
    if (threadIdx.x == 0) {
        float mm = red[0];
        for (int i = 1; i < 16; i++) mm = fmaxf(mm, red[i]);
        Msh = mm;
    }
    __syncthreads();
    float M = Msh;
    float s = 0.f;
    for (int i = threadIdx.x; i < VOCAB; i += blockDim.x) s += expf(out[i] - M);
    s = wave_reduce_sum(s);
    if (lane == 0) red[wid] = s;
    __syncthreads();
    if (threadIdx.x == 0) {
        float ss = 0.f;
        for (int i = 0; i < 16; i++) ss += red[i];
        c[0] = M + logf(ss);
    }
}

// K9: out[v] -= c
__global__ void k_sub(float* out, const float* c) {
    int v = blockIdx.x * blockDim.x + threadIdx.x;
    if (v < VOCAB) out[v] -= c[0];
}

extern "C" void kernel_launch(void* const* d_in, const int* in_sizes, int n_in,
                              void* d_out, int out_size, void* d_ws, size_t ws_size,
                              hipStream_t stream) {
    const int*   x     = (const int*)d_in[0];
    const float* h     = (const float*)d_in[1];   // [1,1,H] -> H floats
    const float* enc   = (const float*)d_in[2];   // [128,H]
    const float* emb   = (const float*)d_in[3];   // [VOCAB,H]
    const float* W_attn= (const float*)d_in[4];   // [128,2H]
    const float* b_attn= (const float*)d_in[5];
    const float* W_comb= (const float*)d_in[6];   // [H,2H]
    const float* b_comb= (const float*)d_in[7];
    const float* w_ih  = (const float*)d_in[8];   // [3H,H]
    const float* w_hh  = (const float*)d_in[9];
    const float* b_ih  = (const float*)d_in[10];
    const float* b_hh  = (const float*)d_in[11];
    const float* W_out = (const float*)d_in[12];  // [VOCAB,H]
    const float* b_out = (const float*)d_in[13];

    float* out      = (float*)d_out;              // [VOCAB] log-probs
    float* out_h    = out + VOCAB;                // [H] h_new
    float* out_attn = out + VOCAB + H;            // [128] attn_w

    float* ws       = (float*)d_ws;
    float* logits128   = ws;            // 128
    float* attn_w      = ws + 128;      // 128
    float* attn_applied= ws + 256;      // 1024
    float* g           = ws + 1280;     // 1024
    float* gi          = ws + 2304;     // 3072
    float* gh          = ws + 5376;     // 3072
    float* lse_c       = ws + 8448;     // 1

    k_attn_logits<<<MAXLEN, 256, 0, stream>>>(x, h, emb, W_attn, b_attn, logits128);
    k_softmax128<<<1, MAXLEN, 0, stream>>>(logits128, attn_w, out_attn);
    k_attn_apply<<<H / 256, 256, 0, stream>>>(attn_w, enc, attn_applied);
    k_combine<<<H / 4, 256, 0, stream>>>(x, emb, attn_applied, W_comb, b_comb, g);
    k_gru_mm<<<(6 * H) / 4, 256, 0, stream>>>(g, h, w_ih, w_hh, b_ih, b_hh, gi, gh);
    k_gates<<<1, H, 0, stream>>>(gi, gh, h, out_h);
    k_out_matvec<<<(VOCAB + 3) / 4, 256, 0, stream>>>(out_h, W_out, b_out, out);
    k_lse<<<1, 1024, 0, stream>>>(out, lse_c);
    k_sub<<<(VOCAB + 255) / 256, 256, 0, stream>>>(out, lse_c);
}

// Round 2
// 74.123 us; speedup vs baseline: 1.1351x; 1.1351x over previous
//
#include <hip/hip_runtime.h>
#include <hip/hip_bf16.h>
#include <math.h>

#define H 1024
#define MAXLEN 128
#define VOCAB 50257
#define NB_OUT ((VOCAB + 3) / 4)   // 12565 blocks, 4 rows (1 per wave) each

__device__ inline float wave_reduce_sum(float v) {
    #pragma unroll
    for (int off = 32; off > 0; off >>= 1) v += __shfl_down(v, off);
    return v;  // lane 0 holds the sum
}

// K1: attn logits[i] = dot(concat(e, h0), W_attn[i]) + b_attn[i], i in [0,128)
__global__ void k_attn_logits(const int* x, const float* h, const float* emb,
                              const float* W_attn, const float* b_attn, float* logits) {
    const int row = blockIdx.x;
    const float4* w4 = (const float4*)(W_attn + row * (2 * H));
    const float4* e4 = (const float4*)(emb + (long long)x[0] * H);
    const float4* h4 = (const float4*)h;
    float acc = 0.f;
    int t = threadIdx.x;  // 256 threads
    #pragma unroll
    for (int i = 0; i < 2; i++) {
        int idx = t + i * 256;  // float4 index into 512-wide row
        float4 wv = w4[idx];
        float4 cv = (idx < 256) ? e4[idx] : h4[idx - 256];
        acc += wv.x * cv.x + wv.y * cv.y + wv.z * cv.z + wv.w * cv.w;
    }
    __shared__ float red[4];
    int lane = t & 63, wid = t >> 6;
    acc = wave_reduce_sum(acc);
    if (lane == 0) red[wid] = acc;
    __syncthreads();
    if (t == 0)
        logits[row] = red[0] + red[1] + red[2] + red[3] + b_attn[row];
}

// K2 (fused softmax + apply): attn_applied[j] = sum_k softmax(logits)[k] * enc[k][j]
// 4 blocks x 256 threads; each block redundantly computes the 128-wide softmax in LDS.
__global__ void k_attn_sm_apply(const float* logits, const float* enc,
                                float* attn_applied, float* out_attn) {
    __shared__ float buf[MAXLEN];
    __shared__ float w[MAXLEN];
    int t = threadIdx.x;  // 256
    if (t < MAXLEN) buf[t] = logits[t];
    __syncthreads();
    float m = -INFINITY;
    #pragma unroll 8
    for (int k = 0; k < MAXLEN; k++) m = fmaxf(m, buf[k]);
    if (t < MAXLEN) w[t] = expf(buf[t] - m);
    __syncthreads();
    float s = 0.f;
    #pragma unroll 8
    for (int k = 0; k < MAXLEN; k++) s += w[k];
    float inv = 1.f / s;
    int j = blockIdx.x * blockDim.x + t;
    float acc = 0.f;
    #pragma unroll 8
    for (int k = 0; k < MAXLEN; k++) acc += w[k] * enc[k * H + j];
    attn_applied[j] = acc * inv;
    if (blockIdx.x == 0 && t < MAXLEN) out_attn[t] = w[t] * inv;
}

// K3: g[row] = relu(dot(concat(e, attn_applied), W_comb[row]) + b_comb[row]); one wave per row
__global__ void k_combine(const int* x, const float* emb, const float* attn_applied,
                          const float* W_comb, const float* b_comb, float* g) {
    int wid = threadIdx.x >> 6, lane = threadIdx.x & 63;
    int row = blockIdx.x * 4 + wid;
    const float4* w4 = (const float4*)(W_comb + (long long)row * (2 * H));
    const float4* e4 = (const float4*)(emb + (long long)x[0] * H);
    const float4* a4 = (const float4*)attn_applied;
    float acc = 0.f;
    #pragma unroll
    for (int i = 0; i < 8; i++) {
        int idx = lane + i * 64;  // float4 index into 512-wide row
        float4 wv = w4[idx];
        float4 cv = (idx < 256) ? e4[idx] : a4[idx - 256];
        acc += wv.x * cv.x + wv.y * cv.y + wv.z * cv.z + wv.w * cv.w;
    }
    acc = wave_reduce_sum(acc);
    if (lane == 0) g[row] = fmaxf(acc + b_comb[row], 0.f);
}

// K4: gi[i] = dot(g, w_ih[i]) + b_ih[i];  gh[i] = dot(h0, w_hh[i]) + b_hh[i]; one wave per row
__global__ void k_gru_mm(const float* g, const float* h,
                         const float* w_ih, const float* w_hh,
                         const float* b_ih, const float* b_hh,
                         float* gi, float* gh) {
    int wid = threadIdx.x >> 6, lane = threadIdx.x & 63;
    int gRow = blockIdx.x * 4 + wid;  // 0..6143
    const float* vec;
    const float* mat;
    const float* bias;
    float* out;
    int row;
    if (gRow < 3 * H) { row = gRow; vec = g; mat = w_ih; bias = b_ih; out = gi; }
    else { row = gRow - 3 * H; vec = h; mat = w_hh; bias = b_hh; out = gh; }
    const float4* w4 = (const float4*)(mat + (long long)row * H);
    const float4* v4 = (const float4*)vec;
    float acc = 0.f;
    #pragma unroll
    for (int i = 0; i < 4; i++) {
        int idx = lane + i * 64;
        float4 wv = w4[idx];
        float4 vv = v4[idx];
        acc += wv.x * vv.x + wv.y * vv.y + wv.z * vv.z + wv.w * vv.w;
    }
    acc = wave_reduce_sum(acc);
    if (lane == 0) out[row] = acc + bias[row];
}

// K5: GRU gate combine -> h_new (written to d_out h slot)
__global__ void k_gates(const float* gi, const float* gh, const float* h, float* h_new) {
    int j = threadIdx.x;  // 1024 threads
    float r = 1.f / (1.f + expf(-(gi[j] + gh[j])));
    float z = 1.f / (1.f + expf(-(gi[j + H] + gh[j + H])));
    float n = tanhf(gi[j + 2 * H] + r * gh[j + 2 * H]);
    h_new[j] = (1.f - z) * n + z * h[j];
}

// K6: logits[v] = dot(h_new, W_out[v]) + b_out[v]; one wave per row.
// Each block also emits a per-block (max, sumexp) partial for the LSE.
__global__ void k_out_matvec(const float* hn, const float* W_out, const float* b_out,
                             float* out, float* pmax, float* psum) {
    int wid = threadIdx.x >> 6, lane = threadIdx.x & 63;
    int row = blockIdx.x * 4 + wid;
    __shared__ float lm[4];
    float logit = -INFINITY;
    if (row < VOCAB) {
        const float4* w4 = (const float4*)(W_out + (long long)row * H);
        const float4* h4 = (const float4*)hn;
        float acc = 0.f;
        #pragma unroll
        for (int i = 0; i < 4; i++) {
            int idx = lane + i * 64;
            float4 wv = w4[idx];
            float4 hv = h4[idx];
            acc += wv.x * hv.x + wv.y * hv.y + wv.z * hv.z + wv.w * hv.w;
        }
        acc = wave_reduce_sum(acc);
        if (lane == 0) { logit = acc + b_out[row]; out[row] = logit; }
    }
    if (lane == 0) lm[wid] = logit;
    __syncthreads();
    if (threadIdx.x == 0) {
        float m = fmaxf(fmaxf(lm[0], lm[1]), fmaxf(lm[2], lm[3]));
        float s = 0.f;
        #pragma unroll
        for (int i = 0; i < 4; i++)
            if (lm[i] != -INFINITY) s += expf(lm[i] - m);
        pmax[blockIdx.x] = m;
        psum[blockIdx.x] = s;
    }
}

// K7: merge per-block partials: c = M + log(sum_b s_b * exp(m_b - M))
__global__ void k_lse_merge(const float* pmax, const float* psum, float* c) {
    __shared__ float red[16];
    __shared__ float Msh;
    int lane = threadIdx.x & 63, wid = threadIdx.x >> 6;
    float m = -INFINITY;
    for (int i = threadIdx.x; i < NB_OUT; i += blockDim.x) m = fmaxf(m, pmax[i]);
    #pragma unroll
    for (int off = 32; off > 0; off >>= 1) m = fmaxf(m, __shfl_down(m, off));
    if (lane == 0) red[wid] = m;
    __syncthreads();
    if (threadIdx.x == 0) {
        float mm = red[0];
        for (int i = 1; i < 16; i++) mm = fmaxf(mm, red[i]);
        Msh = mm;
    }
    __syncthreads();
    float M = Msh;
    float s = 0.f;
    for (int i = threadIdx.x; i < NB_OUT; i += blockDim.x) s += psum[i] * expf(pmax[i] - M);
    s = wave_reduce_sum(s);
    if (lane == 0) red[wid] = s;
    __syncthreads();
    if (threadIdx.x == 0) {
        float ss = 0.f;
        for (int i = 0; i < 16; i++) ss += red[i];
        c[0] = M + logf(ss);
    }
}

// K8: out[v] -= c
__global__ void k_sub(float* out, const float* c) {
    int v = blockIdx.x * blockDim.x + threadIdx.x;
    if (v < VOCAB) out[v] -= c[0];
}

extern "C" void kernel_launch(void* const* d_in, const int* in_sizes, int n_in,
                              void* d_out, int out_size, void* d_ws, size_t ws_size,
                              hipStream_t stream) {
    const int*   x     = (const int*)d_in[0];
    const float* h     = (const float*)d_in[1];   // [1,1,H] -> H floats
    const float* enc   = (const float*)d_in[2];   // [128,H]
    const float* emb   = (const float*)d_in[3];   // [VOCAB,H]
    const float* W_attn= (const float*)d_in[4];   // [128,2H]
    const float* b_attn= (const float*)d_in[5];
    const float* W_comb= (const float*)d_in[6];   // [H,2H]
    const float* b_comb= (const float*)d_in[7];
    const float* w_ih  = (const float*)d_in[8];   // [3H,H]
    const float* w_hh  = (const float*)d_in[9];
    const float* b_ih  = (const float*)d_in[10];
    const float* b_hh  = (const float*)d_in[11];
    const float* W_out = (const float*)d_in[12];  // [VOCAB,H]
    const float* b_out = (const float*)d_in[13];

    float* out      = (float*)d_out;              // [VOCAB] log-probs
    float* out_h    = out + VOCAB;                // [H] h_new
    float* out_attn = out + VOCAB + H;            // [128] attn_w

    float* ws       = (float*)d_ws;
    float* logits128   = ws;            // 128
    float* attn_applied= ws + 256;      // 1024
    float* g           = ws + 1280;     // 1024
    float* gi          = ws + 2304;     // 3072
    float* gh          = ws + 5376;     // 3072
    float* lse_c       = ws + 8448;     // 1
    float* pmax        = ws + 9216;     // NB_OUT (12565)
    float* psum        = ws + 22272;    // NB_OUT

    k_attn_logits<<<MAXLEN, 256, 0, stream>>>(x, h, emb, W_attn, b_attn, logits128);
    k_attn_sm_apply<<<H / 256, 256, 0, stream>>>(logits128, enc, attn_applied, out_attn);
    k_combine<<<H / 4, 256, 0, stream>>>(x, emb, attn_applied, W_comb, b_comb, g);
    k_gru_mm<<<(6 * H) / 4, 256, 0, stream>>>(g, h, w_ih, w_hh, b_ih, b_hh, gi, gh);
    k_gates<<<1, H, 0, stream>>>(gi, gh, h, out_h);
    k_out_matvec<<<NB_OUT, 256, 0, stream>>>(out_h, W_out, b_out, out, pmax, psum);
    k_lse_merge<<<1, 1024, 0, stream>>>(pmax, psum, lse_c);
    k_sub<<<(VOCAB + 255) / 256, 256, 0, stream>>>(out, lse_c);
}